// Round 4
// baseline (533.157 us; speedup 1.0000x reference)
//
#include <hip/hip_runtime.h>
#include <hip/hip_bf16.h>
#include <math.h>

// ---------------------------------------------------------------------------
// out[s] = (sum_i gate_i * x_i) @ Wm + (sum_i gate_i) * bm
// gate_i = softmax-with-eps over h_i = x_i.Wg + bg + pow*ln(w_i)
// index is SORTED -> segments are contiguous row ranges.
// ---------------------------------------------------------------------------

// K1: seg_start[s] = first row i with index[i] >= s ; seg_start[S] = N
// Also zeroes the K2 work-stealing counter (deterministic per launch).
__global__ __launch_bounds__(256) void k1_seg_offsets(const int* __restrict__ index,
                                                      int* __restrict__ seg_start,
                                                      int* __restrict__ ctr,
                                                      int N, int S) {
    int i = blockIdx.x * blockDim.x + threadIdx.x;
    if (i >= N) return;
    if (i == 0) *ctr = 0;
    int cur  = index[i];
    int prev = (i == 0) ? -1 : index[i - 1];
    for (int s = prev + 1; s <= cur; ++s) seg_start[s] = i;
    if (i == N - 1) {
        for (int s = cur + 1; s <= S; ++s) seg_start[s] = N;
    }
}

// K2: wave = 4 groups x 16 lanes; each group owns one row per 4-row step
// (float8 per lane). Per-group online softmax with defer-rescale (THR=8),
// flash-combine across groups per segment. Waves pull segments from a global
// pool (atomic counter) in batches of 2 -> near-perfect load balance.
#define K2_BATCH 2
__global__ __launch_bounds__(256) void k2_seg_softmax_pool(
    const float* __restrict__ x, const float* __restrict__ w,
    const float* __restrict__ Wg, const float* __restrict__ bg,
    const float* __restrict__ pw_, const int* __restrict__ seg_start,
    float* __restrict__ t, float* __restrict__ sgate,
    int* __restrict__ ctr, int S) {
    int lane = threadIdx.x & 63;
    int grp  = lane >> 4;        // which row of the 4-row step
    int pos  = lane & 15;        // feature slice [8*pos, 8*pos+8)

    float4 wg0 = *reinterpret_cast<const float4*>(Wg + pos * 8);
    float4 wg1 = *reinterpret_cast<const float4*>(Wg + pos * 8 + 4);
    float bgv = bg[0];
    float pw  = pw_[0];

    while (true) {
        int s0;
        if (lane == 0) s0 = atomicAdd(ctr, K2_BATCH);
        s0 = __shfl(s0, 0);
        if (s0 >= S) break;
        int sEnd = s0 + K2_BATCH; if (sEnd > S) sEnd = S;

        for (int seg = s0; seg < sEnd; ++seg) {
            int start = seg_start[seg], end = seg_start[seg + 1];

            float mg = -INFINITY, ssum = 0.f;
            float acc[8];
            #pragma unroll
            for (int j = 0; j < 8; ++j) acc[j] = 0.f;

            if (start < end) {
                int row0 = start + grp;
                bool v0 = row0 < end;
                const float* xp0 = x + (size_t)row0 * 128 + pos * 8;
                float4 a = v0 ? *reinterpret_cast<const float4*>(xp0)     : make_float4(0,0,0,0);
                float4 b = v0 ? *reinterpret_cast<const float4*>(xp0 + 4) : make_float4(0,0,0,0);
                float wv = v0 ? w[row0] : 1.f;

                for (int i0 = start; i0 < end; i0 += 4) {
                    // prefetch next step
                    int rn = i0 + 4 + grp;
                    bool vn = rn < end;
                    const float* xpn = x + (size_t)rn * 128 + pos * 8;
                    float4 an = vn ? *reinterpret_cast<const float4*>(xpn)     : make_float4(0,0,0,0);
                    float4 bn = vn ? *reinterpret_cast<const float4*>(xpn + 4) : make_float4(0,0,0,0);
                    float wn = vn ? w[rn] : 1.f;

                    bool v = (i0 + grp) < end;
                    float p = a.x*wg0.x + a.y*wg0.y + a.z*wg0.z + a.w*wg0.w
                            + b.x*wg1.x + b.y*wg1.y + b.z*wg1.z + b.w*wg1.w;
                    p += __shfl_xor(p, 1);
                    p += __shfl_xor(p, 2);
                    p += __shfl_xor(p, 4);
                    p += __shfl_xor(p, 8);
                    float h = v ? (p + bgv + pw * __logf(wv)) : -1e30f;

                    if (v && h > mg + 8.f) {        // defer-rescale: rarely taken
                        float sc = __expf(mg - h);  // mg=-inf first time -> 0
                        ssum *= sc;
                        #pragma unroll
                        for (int j = 0; j < 8; ++j) acc[j] *= sc;
                        mg = h;
                    }
                    float e = v ? __expf(h - mg) : 0.f;   // bounded by e^8
                    ssum += e;
                    acc[0] += e * a.x; acc[1] += e * a.y; acc[2] += e * a.z; acc[3] += e * a.w;
                    acc[4] += e * b.x; acc[5] += e * b.y; acc[6] += e * b.z; acc[7] += e * b.w;

                    a = an; b = bn; wv = wn;
                }
            }

            // flash-combine the 4 groups (xor 16, then 32)
            #pragma unroll
            for (int off = 16; off <= 32; off <<= 1) {
                float mo = __shfl_xor(mg, off);
                float so = __shfl_xor(ssum, off);
                float ao[8];
                #pragma unroll
                for (int j = 0; j < 8; ++j) ao[j] = __shfl_xor(acc[j], off);
                float mc = fmaxf(mg, mo);
                float c1 = (mg > -1e37f) ? __expf(mg - mc) : 0.f;   // -inf guard
                float c2 = (mo > -1e37f) ? __expf(mo - mc) : 0.f;
                ssum = ssum * c1 + so * c2;
                #pragma unroll
                for (int j = 0; j < 8; ++j) acc[j] = acc[j] * c1 + ao[j] * c2;
                mg = mc;
            }

            float inv = 1.f / (ssum + 1e-10f);
            if (lane < 16) {
                float* tp = t + (size_t)seg * 128 + pos * 8;
                *reinterpret_cast<float4*>(tp) =
                    make_float4(acc[0]*inv, acc[1]*inv, acc[2]*inv, acc[3]*inv);
                *reinterpret_cast<float4*>(tp + 4) =
                    make_float4(acc[4]*inv, acc[5]*inv, acc[6]*inv, acc[7]*inv);
            }
            if (lane == 0) sgate[seg] = ssum * inv;   // sum of normalized gates
        }
    }
}

// K3: out[row][:] = t[row][:] @ Wm + sgate[row] * bm
// 512 threads: 8 waves x 8 rows = 64 rows/block; Wm staged once in 64 KiB LDS.
__global__ __launch_bounds__(512) void k3_out_gemm(
    const float* __restrict__ t, const float* __restrict__ Wm,
    const float* __restrict__ bm, const float* __restrict__ sgate,
    float* __restrict__ out, int S) {
    __shared__ float2 lwm[128][64];   // lwm[k][l] = (Wm[k][l], Wm[k][l+64])
    int tid = threadIdx.x;
    for (int idx = tid; idx < 128 * 64; idx += 512) {
        int k = idx >> 6, l = idx & 63;
        lwm[k][l] = make_float2(Wm[k * 128 + l], Wm[k * 128 + 64 + l]);
    }
    __syncthreads();

    int wave = tid >> 6, lane = tid & 63;
    int row0 = (blockIdx.x * 8 + wave) * 8;       // 8 rows per wave
    if (row0 >= S) return;

    const float* tb = t + (size_t)__builtin_amdgcn_readfirstlane(row0) * 128;

    float accx[8], accy[8];
    #pragma unroll
    for (int r = 0; r < 8; ++r) { accx[r] = 0.f; accy[r] = 0.f; }

    for (int k = 0; k < 128; k += 4) {
        float2 w0 = lwm[k][lane],     w1 = lwm[k + 1][lane];
        float2 w2 = lwm[k + 2][lane], w3 = lwm[k + 3][lane];
        #pragma unroll
        for (int r = 0; r < 8; ++r) {
            const float* tr = tb + r * 128 + k;   // uniform -> s_load
            float t0 = tr[0], t1 = tr[1], t2 = tr[2], t3 = tr[3];
            accx[r] += t0 * w0.x; accy[r] += t0 * w0.y;
            accx[r] += t1 * w1.x; accy[r] += t1 * w1.y;
            accx[r] += t2 * w2.x; accy[r] += t2 * w2.y;
            accx[r] += t3 * w3.x; accy[r] += t3 * w3.y;
        }
    }

    float bmx = bm[lane], bmy = bm[lane + 64];
    #pragma unroll
    for (int r = 0; r < 8; ++r) {
        int row = row0 + r;
        if (row < S) {
            float sg = sgate[row];
            out[(size_t)row * 128 + lane]      = accx[r] + sg * bmx;
            out[(size_t)row * 128 + lane + 64] = accy[r] + sg * bmy;
        }
    }
}

extern "C" void kernel_launch(void* const* d_in, const int* in_sizes, int n_in,
                              void* d_out, int out_size, void* d_ws, size_t ws_size,
                              hipStream_t stream) {
    const float* x       = (const float*)d_in[0];
    const float* weights = (const float*)d_in[1];
    const float* Wg      = (const float*)d_in[2];
    const float* bg      = (const float*)d_in[3];
    const float* Wm      = (const float*)d_in[4];
    const float* bm      = (const float*)d_in[5];
    const float* pow_    = (const float*)d_in[6];
    const int*   index   = (const int*)d_in[7];
    float* out = (float*)d_out;

    int N = in_sizes[1];          // weights is [N,1]
    int S = out_size / 128;       // out is [S,128]

    // workspace layout
    char* ws = (char*)d_ws;
    int* seg_start = (int*)ws;                                  // (S+1) ints
    size_t off = (((size_t)(S + 1) * 4) + 255) & ~(size_t)255;
    float* sgate = (float*)(ws + off);                          // S floats
    off += (((size_t)S * 4) + 255) & ~(size_t)255;
    float* t = (float*)(ws + off);                              // (S+64)*128 floats (pad for K3 over-read)
    off += (((size_t)(S + 64) * 128 * 4) + 255) & ~(size_t)255;
    int* ctr = (int*)(ws + off);                                // work-steal counter

    k1_seg_offsets<<<(N + 255) / 256, 256, 0, stream>>>(index, seg_start, ctr, N, S);
    k2_seg_softmax_pool<<<2048, 256, 0, stream>>>(x, weights, Wg, bg, pow_,
                                                  seg_start, t, sgate, ctr, S);
    k3_out_gemm<<<(S + 63) / 64, 512, 0, stream>>>(t, Wm, bm, sgate, out, S);
}

// Round 5
// 187.421 us; speedup vs baseline: 2.8447x; 2.8447x over previous
//
#include <hip/hip_runtime.h>
#include <hip/hip_bf16.h>
#include <math.h>

// ---------------------------------------------------------------------------
// out[s] = (sum_i gate_i * x_i) @ Wm + (sum_i gate_i) * bm
// gate_i = softmax-with-eps over h_i = x_i.Wg + bg + pow*ln(w_i)
// index is SORTED -> segments are contiguous row ranges.
// ---------------------------------------------------------------------------

// K1: seg_start[s] = first row i with index[i] >= s ; seg_start[S] = N
__global__ __launch_bounds__(256) void k1_seg_offsets(const int* __restrict__ index,
                                                      int* __restrict__ seg_start,
                                                      int N, int S) {
    int i = blockIdx.x * blockDim.x + threadIdx.x;
    if (i >= N) return;
    int cur  = index[i];
    int prev = (i == 0) ? -1 : index[i - 1];
    for (int s = prev + 1; s <= cur; ++s) seg_start[s] = i;
    if (i == N - 1) {
        for (int s = cur + 1; s <= S; ++s) seg_start[s] = N;
    }
}

__device__ __forceinline__ void zero_seg(float* __restrict__ t,
                                         float* __restrict__ sgate,
                                         int seg, int lane) {
    if (lane < 16) {
        float* tp = t + (size_t)seg * 128 + lane * 8;
        *reinterpret_cast<float4*>(tp)     = make_float4(0.f, 0.f, 0.f, 0.f);
        *reinterpret_cast<float4*>(tp + 4) = make_float4(0.f, 0.f, 0.f, 0.f);
    }
    if (lane == 0) sgate[seg] = 0.f;
}

// K2: persistent waves. Wave gw owns contiguous segments [gw*S/W,(gw+1)*S/W).
// Wave = 4 groups x 16 lanes; one row per group per step (float8/lane).
// 2-deep prefetch pipeline that CROSSES segment boundaries: a prefetch cursor
// walks (seg, step) 2 steps ahead of compute; segment bounds live one-per-lane
// (shfl lookup). Loads unconditional (clamped addr); predicate at compute.
// Per-group online softmax with defer-rescale (THR=8); flash-combine per seg.
__global__ __launch_bounds__(256) void k2_seg_softmax_pool(
    const float* __restrict__ x, const float* __restrict__ wt,
    const float* __restrict__ Wg, const float* __restrict__ bg,
    const float* __restrict__ pw_, const int* __restrict__ seg_start,
    float* __restrict__ t, float* __restrict__ sgate, int S) {
    int lane = threadIdx.x & 63;
    int grp  = lane >> 4;        // which row of the 4-row step
    int pos  = lane & 15;        // feature slice [8*pos, 8*pos+8)
    int gw   = blockIdx.x * 4 + (threadIdx.x >> 6);
    long long W = (long long)gridDim.x * 4;

    int sLo = (int)((long long)gw * S / W);
    int sHi = (int)(((long long)gw + 1) * S / W);
    int nSegs = sHi - sLo;
    if (nSegs <= 0) return;

    int bidx = sLo + lane; if (bidx > S) bidx = S;
    int bnd = seg_start[bidx];           // lane j holds bound of seg sLo+j

    // ---- compute cursor init (skip+zero leading empty segments) ----
    int ck = 0;
    int ci0  = __shfl(bnd, 0);
    int cend = __shfl(bnd, 1);
    while (cend <= ci0) {                // empty segment
        zero_seg(t, sgate, sLo + ck, lane);
        ++ck;
        if (ck >= nSegs) return;
        cend = __shfl(bnd, ck + 1);
    }
    // ---- prefetch cursor starts where compute starts ----
    int pk = ck, pi0 = ci0, pend = cend;

    float4 wg0 = *reinterpret_cast<const float4*>(Wg + pos * 8);
    float4 wg1 = *reinterpret_cast<const float4*>(Wg + pos * 8 + 4);
    float bgv = bg[0];
    float pw  = pw_[0];

    float4 a0, b0, a1, b1, a2, b2;
    float  w0, w1, w2;

    auto issue = [&](float4& A, float4& B, float& Wv) {
        int r  = pi0 + grp;
        int rc = (r < pend) ? r : (pend - 1);   // clamp: always a valid row
        const float* p = x + (size_t)rc * 128 + pos * 8;
        A  = *reinterpret_cast<const float4*>(p);
        B  = *reinterpret_cast<const float4*>(p + 4);
        Wv = wt[rc];
    };
    auto padv = [&]() {
        if (pi0 + 4 < pend) { pi0 += 4; return; }
        pi0 = pend;
        ++pk;
        while (pk < nSegs) {
            int e = __shfl(bnd, pk + 1);
            if (e > pi0) { pend = e; return; }
            ++pk;
        }
        // pk == nSegs: pipeline tail; addresses keep clamping to pend-1
    };

    issue(a0, b0, w0); padv();
    issue(a1, b1, w1); padv();

    float mg = -INFINITY, ssum = 0.f;
    float acc[8];
    #pragma unroll
    for (int j = 0; j < 8; ++j) acc[j] = 0.f;

    while (true) {
        issue(a2, b2, w2); padv();

        // ---- compute current step (a0,b0,w0) at (ci0, cend) ----
        bool v = (ci0 + grp) < cend;
        float p = a0.x*wg0.x + a0.y*wg0.y + a0.z*wg0.z + a0.w*wg0.w
                + b0.x*wg1.x + b0.y*wg1.y + b0.z*wg1.z + b0.w*wg1.w;
        p += __shfl_xor(p, 1);
        p += __shfl_xor(p, 2);
        p += __shfl_xor(p, 4);
        p += __shfl_xor(p, 8);
        float h = v ? (p + bgv + pw * __logf(w0)) : -1e30f;

        if (v && h > mg + 8.f) {          // defer-rescale: rarely taken
            float sc = __expf(mg - h);    // mg=-inf first time -> 0
            ssum *= sc;
            #pragma unroll
            for (int j = 0; j < 8; ++j) acc[j] *= sc;
            mg = h;
        }
        float e = v ? __expf(h - mg) : 0.f;   // bounded by e^8
        ssum += e;
        acc[0] += e * a0.x; acc[1] += e * a0.y; acc[2] += e * a0.z; acc[3] += e * a0.w;
        acc[4] += e * b0.x; acc[5] += e * b0.y; acc[6] += e * b0.z; acc[7] += e * b0.w;

        bool segLast = (ci0 + 4 >= cend);
        if (segLast) {
            // flash-combine the 4 groups (xor 16, then 32)
            #pragma unroll
            for (int off = 16; off <= 32; off <<= 1) {
                float mo = __shfl_xor(mg, off);
                float so = __shfl_xor(ssum, off);
                float ao[8];
                #pragma unroll
                for (int j = 0; j < 8; ++j) ao[j] = __shfl_xor(acc[j], off);
                float mc = fmaxf(mg, mo);
                float c1 = (mg > -1e37f) ? __expf(mg - mc) : 0.f;   // -inf guard
                float c2 = (mo > -1e37f) ? __expf(mo - mc) : 0.f;
                ssum = ssum * c1 + so * c2;
                #pragma unroll
                for (int j = 0; j < 8; ++j) acc[j] = acc[j] * c1 + ao[j] * c2;
                mg = mc;
            }
            int seg = sLo + ck;
            float inv = 1.f / (ssum + 1e-10f);
            if (lane < 16) {
                float* tp = t + (size_t)seg * 128 + pos * 8;
                *reinterpret_cast<float4*>(tp) =
                    make_float4(acc[0]*inv, acc[1]*inv, acc[2]*inv, acc[3]*inv);
                *reinterpret_cast<float4*>(tp + 4) =
                    make_float4(acc[4]*inv, acc[5]*inv, acc[6]*inv, acc[7]*inv);
            }
            if (lane == 0) sgate[seg] = ssum * inv;
            mg = -INFINITY; ssum = 0.f;
            #pragma unroll
            for (int j = 0; j < 8; ++j) acc[j] = 0.f;
        }

        // ---- advance compute cursor ----
        if (!segLast) {
            ci0 += 4;
        } else {
            ci0 = cend;
            ++ck;
            while (ck < nSegs) {
                int e2 = __shfl(bnd, ck + 1);
                if (e2 > ci0) { cend = e2; break; }
                zero_seg(t, sgate, sLo + ck, lane);   // empty segment
                ++ck;
            }
            if (ck >= nSegs) break;
        }

        // rotate pipeline buffers
        a0 = a1; b0 = b1; w0 = w1;
        a1 = a2; b1 = b2; w1 = w2;
    }
}

// K3: out[row][:] = t[row][:] @ Wm + sgate[row] * bm
// 512 threads: 8 waves x 8 rows = 64 rows/block; Wm staged once in 64 KiB LDS.
__global__ __launch_bounds__(512) void k3_out_gemm(
    const float* __restrict__ t, const float* __restrict__ Wm,
    const float* __restrict__ bm, const float* __restrict__ sgate,
    float* __restrict__ out, int S) {
    __shared__ float2 lwm[128][64];   // lwm[k][l] = (Wm[k][l], Wm[k][l+64])
    int tid = threadIdx.x;
    for (int idx = tid; idx < 128 * 64; idx += 512) {
        int k = idx >> 6, l = idx & 63;
        lwm[k][l] = make_float2(Wm[k * 128 + l], Wm[k * 128 + 64 + l]);
    }
    __syncthreads();

    int wave = tid >> 6, lane = tid & 63;
    int row0 = (blockIdx.x * 8 + wave) * 8;       // 8 rows per wave
    if (row0 >= S) return;

    const float* tb = t + (size_t)__builtin_amdgcn_readfirstlane(row0) * 128;

    float accx[8], accy[8];
    #pragma unroll
    for (int r = 0; r < 8; ++r) { accx[r] = 0.f; accy[r] = 0.f; }

    for (int k = 0; k < 128; k += 4) {
        float2 w0 = lwm[k][lane],     w1 = lwm[k + 1][lane];
        float2 w2 = lwm[k + 2][lane], w3 = lwm[k + 3][lane];
        #pragma unroll
        for (int r = 0; r < 8; ++r) {
            const float* tr = tb + r * 128 + k;   // uniform -> s_load
            float t0 = tr[0], t1 = tr[1], t2 = tr[2], t3 = tr[3];
            accx[r] += t0 * w0.x; accy[r] += t0 * w0.y;
            accx[r] += t1 * w1.x; accy[r] += t1 * w1.y;
            accx[r] += t2 * w2.x; accy[r] += t2 * w2.y;
            accx[r] += t3 * w3.x; accy[r] += t3 * w3.y;
        }
    }

    float bmx = bm[lane], bmy = bm[lane + 64];
    #pragma unroll
    for (int r = 0; r < 8; ++r) {
        int row = row0 + r;
        if (row < S) {
            float sg = sgate[row];
            out[(size_t)row * 128 + lane]      = accx[r] + sg * bmx;
            out[(size_t)row * 128 + lane + 64] = accy[r] + sg * bmy;
        }
    }
}

extern "C" void kernel_launch(void* const* d_in, const int* in_sizes, int n_in,
                              void* d_out, int out_size, void* d_ws, size_t ws_size,
                              hipStream_t stream) {
    const float* x       = (const float*)d_in[0];
    const float* weights = (const float*)d_in[1];
    const float* Wg      = (const float*)d_in[2];
    const float* bg      = (const float*)d_in[3];
    const float* Wm      = (const float*)d_in[4];
    const float* bm      = (const float*)d_in[5];
    const float* pow_    = (const float*)d_in[6];
    const int*   index   = (const int*)d_in[7];
    float* out = (float*)d_out;

    int N = in_sizes[1];          // weights is [N,1]
    int S = out_size / 128;       // out is [S,128]

    // workspace layout
    char* ws = (char*)d_ws;
    int* seg_start = (int*)ws;                                  // (S+1) ints
    size_t off = (((size_t)(S + 1) * 4) + 255) & ~(size_t)255;
    float* sgate = (float*)(ws + off);                          // S floats
    off += (((size_t)S * 4) + 255) & ~(size_t)255;
    float* t = (float*)(ws + off);                              // (S+64)*128 floats (pad for K3 over-read)

    k1_seg_offsets<<<(N + 255) / 256, 256, 0, stream>>>(index, seg_start, N, S);
    k2_seg_softmax_pool<<<2048, 256, 0, stream>>>(x, weights, Wg, bg, pow_,
                                                  seg_start, t, sgate, S);
    k3_out_gemm<<<(S + 63) / 64, 512, 0, stream>>>(t, Wm, bm, sgate, out, S);
}

// Round 6
// 162.705 us; speedup vs baseline: 3.2768x; 1.1519x over previous
//
#include <hip/hip_runtime.h>
#include <hip/hip_bf16.h>
#include <math.h>

// ---------------------------------------------------------------------------
// out[s] = (sum_i gate_i * x_i) @ Wm + (sum_i gate_i) * bm
// gate_i = softmax-with-eps over h_i = x_i.Wg + bg + pow*ln(w_i)
// index is SORTED -> segments are contiguous row ranges.
// ---------------------------------------------------------------------------

// K1: seg_start[s] = first row i with index[i] >= s ; seg_start[S] = N
__global__ __launch_bounds__(256) void k1_seg_offsets(const int* __restrict__ index,
                                                      int* __restrict__ seg_start,
                                                      int N, int S) {
    int i = blockIdx.x * blockDim.x + threadIdx.x;
    if (i >= N) return;
    int cur  = index[i];
    int prev = (i == 0) ? -1 : index[i - 1];
    for (int s = prev + 1; s <= cur; ++s) seg_start[s] = i;
    if (i == N - 1) {
        for (int s = cur + 1; s <= S; ++s) seg_start[s] = N;
    }
}

// K2: one wave per segment (oversubscribed grid -> HW self-balancing).
// Wave = 4 groups x 16 lanes; one row per group per step (float8/lane).
// 2-deep prefetch with CLAMPED UNCONDITIONAL loads (no data-selects ->
// no forced vmcnt wait in the issuing iteration); predicate at compute.
// Per-group online softmax with defer-rescale (THR=8); flash-combine per seg.
__global__ __launch_bounds__(256) void k2_seg_softmax_pool(
    const float* __restrict__ x, const float* __restrict__ wt,
    const float* __restrict__ Wg, const float* __restrict__ bg,
    const float* __restrict__ pw_, const int* __restrict__ seg_start,
    float* __restrict__ t, float* __restrict__ sgate, int S) {
    int gwid = (int)((blockIdx.x * 256 + threadIdx.x) >> 6);
    if (gwid >= S) return;
    int lane = threadIdx.x & 63;
    int grp  = lane >> 4;        // which row of the 4-row step
    int pos  = lane & 15;        // feature slice [8*pos, 8*pos+8)

    int start = seg_start[gwid], end = seg_start[gwid + 1];

    if (start >= end) {          // empty segment: exact zeros
        if (lane < 16) {
            float* tp = t + (size_t)gwid * 128 + pos * 8;
            *reinterpret_cast<float4*>(tp)     = make_float4(0.f, 0.f, 0.f, 0.f);
            *reinterpret_cast<float4*>(tp + 4) = make_float4(0.f, 0.f, 0.f, 0.f);
        }
        if (lane == 0) sgate[gwid] = 0.f;
        return;
    }

    float4 wg0 = *reinterpret_cast<const float4*>(Wg + pos * 8);
    float4 wg1 = *reinterpret_cast<const float4*>(Wg + pos * 8 + 4);
    float bgv = bg[0];
    float pw  = pw_[0];

    int nsteps = (end - start + 3) >> 2;
    int last   = end - 1;

    float4 a0, b0, a1, b1, a2, b2;
    float  w0, w1, w2;

    // clamped unconditional issue for step s
    auto issue = [&](int s, float4& A, float4& B, float& Wv) {
        int r  = start + 4 * s + grp;
        int rc = (r < last) ? r : last;           // clamp: always valid
        const float* p = x + (size_t)rc * 128 + pos * 8;
        A  = *reinterpret_cast<const float4*>(p);
        B  = *reinterpret_cast<const float4*>(p + 4);
        Wv = wt[rc];
    };

    issue(0, a0, b0, w0);
    issue(1, a1, b1, w1);

    float mg = -INFINITY, ssum = 0.f;
    float acc[8];
    #pragma unroll
    for (int j = 0; j < 8; ++j) acc[j] = 0.f;

    for (int s = 0; s < nsteps; ++s) {
        issue(s + 2, a2, b2, w2);     // clamped beyond end: harmless L1 hit

        bool v = (start + 4 * s + grp) < end;
        // lw computed in parallel with the shfl-reduce chain (independent)
        float lw = fmaf(pw, __logf(w0), bgv);
        float p = a0.x*wg0.x + a0.y*wg0.y + a0.z*wg0.z + a0.w*wg0.w
                + b0.x*wg1.x + b0.y*wg1.y + b0.z*wg1.z + b0.w*wg1.w;
        p += __shfl_xor(p, 1);
        p += __shfl_xor(p, 2);
        p += __shfl_xor(p, 4);
        p += __shfl_xor(p, 8);
        float h = v ? (p + lw) : -1e30f;

        if (v && h > mg + 8.f) {          // defer-rescale: rarely taken
            float sc = __expf(mg - h);    // mg=-inf first time -> 0
            ssum *= sc;
            #pragma unroll
            for (int j = 0; j < 8; ++j) acc[j] *= sc;
            mg = h;
        }
        float e = v ? __expf(h - mg) : 0.f;   // bounded by e^8
        ssum += e;
        acc[0] += e * a0.x; acc[1] += e * a0.y; acc[2] += e * a0.z; acc[3] += e * a0.w;
        acc[4] += e * b0.x; acc[5] += e * b0.y; acc[6] += e * b0.z; acc[7] += e * b0.w;

        a0 = a1; b0 = b1; w0 = w1;
        a1 = a2; b1 = b2; w1 = w2;
    }

    // flash-combine the 4 groups (xor 16, then 32)
    #pragma unroll
    for (int off = 16; off <= 32; off <<= 1) {
        float mo = __shfl_xor(mg, off);
        float so = __shfl_xor(ssum, off);
        float ao[8];
        #pragma unroll
        for (int j = 0; j < 8; ++j) ao[j] = __shfl_xor(acc[j], off);
        float mc = fmaxf(mg, mo);
        float c1 = (mg > -1e37f) ? __expf(mg - mc) : 0.f;   // -inf guard
        float c2 = (mo > -1e37f) ? __expf(mo - mc) : 0.f;
        ssum = ssum * c1 + so * c2;
        #pragma unroll
        for (int j = 0; j < 8; ++j) acc[j] = acc[j] * c1 + ao[j] * c2;
        mg = mc;
    }

    float inv = 1.f / (ssum + 1e-10f);
    if (lane < 16) {
        float* tp = t + (size_t)gwid * 128 + pos * 8;
        *reinterpret_cast<float4*>(tp) =
            make_float4(acc[0]*inv, acc[1]*inv, acc[2]*inv, acc[3]*inv);
        *reinterpret_cast<float4*>(tp + 4) =
            make_float4(acc[4]*inv, acc[5]*inv, acc[6]*inv, acc[7]*inv);
    }
    if (lane == 0) sgate[gwid] = ssum * inv;   // sum of normalized gates
}

// K3: out[row][:] = t[row][:] @ Wm + sgate[row] * bm
// 512 threads: 8 waves x 8 rows = 64 rows/block; Wm staged once in 64 KiB LDS.
__global__ __launch_bounds__(512) void k3_out_gemm(
    const float* __restrict__ t, const float* __restrict__ Wm,
    const float* __restrict__ bm, const float* __restrict__ sgate,
    float* __restrict__ out, int S) {
    __shared__ float2 lwm[128][64];   // lwm[k][l] = (Wm[k][l], Wm[k][l+64])
    int tid = threadIdx.x;
    for (int idx = tid; idx < 128 * 64; idx += 512) {
        int k = idx >> 6, l = idx & 63;
        lwm[k][l] = make_float2(Wm[k * 128 + l], Wm[k * 128 + 64 + l]);
    }
    __syncthreads();

    int wave = tid >> 6, lane = tid & 63;
    int row0 = (blockIdx.x * 8 + wave) * 8;       // 8 rows per wave
    if (row0 >= S) return;

    const float* tb = t + (size_t)__builtin_amdgcn_readfirstlane(row0) * 128;

    float accx[8], accy[8];
    #pragma unroll
    for (int r = 0; r < 8; ++r) { accx[r] = 0.f; accy[r] = 0.f; }

    for (int k = 0; k < 128; k += 4) {
        float2 w0 = lwm[k][lane],     w1 = lwm[k + 1][lane];
        float2 w2 = lwm[k + 2][lane], w3 = lwm[k + 3][lane];
        #pragma unroll
        for (int r = 0; r < 8; ++r) {
            const float* tr = tb + r * 128 + k;   // uniform -> s_load
            float t0 = tr[0], t1 = tr[1], t2 = tr[2], t3 = tr[3];
            accx[r] += t0 * w0.x; accy[r] += t0 * w0.y;
            accx[r] += t1 * w1.x; accy[r] += t1 * w1.y;
            accx[r] += t2 * w2.x; accy[r] += t2 * w2.y;
            accx[r] += t3 * w3.x; accy[r] += t3 * w3.y;
        }
    }

    float bmx = bm[lane], bmy = bm[lane + 64];
    #pragma unroll
    for (int r = 0; r < 8; ++r) {
        int row = row0 + r;
        if (row < S) {
            float sg = sgate[row];
            out[(size_t)row * 128 + lane]      = accx[r] + sg * bmx;
            out[(size_t)row * 128 + lane + 64] = accy[r] + sg * bmy;
        }
    }
}

extern "C" void kernel_launch(void* const* d_in, const int* in_sizes, int n_in,
                              void* d_out, int out_size, void* d_ws, size_t ws_size,
                              hipStream_t stream) {
    const float* x       = (const float*)d_in[0];
    const float* weights = (const float*)d_in[1];
    const float* Wg      = (const float*)d_in[2];
    const float* bg      = (const float*)d_in[3];
    const float* Wm      = (const float*)d_in[4];
    const float* bm      = (const float*)d_in[5];
    const float* pow_    = (const float*)d_in[6];
    const int*   index   = (const int*)d_in[7];
    float* out = (float*)d_out;

    int N = in_sizes[1];          // weights is [N,1]
    int S = out_size / 128;       // out is [S,128]

    // workspace layout
    char* ws = (char*)d_ws;
    int* seg_start = (int*)ws;                                  // (S+1) ints
    size_t off = (((size_t)(S + 1) * 4) + 255) & ~(size_t)255;
    float* sgate = (float*)(ws + off);                          // S floats
    off += (((size_t)S * 4) + 255) & ~(size_t)255;
    float* t = (float*)(ws + off);                              // (S+64)*128 floats (pad for K3 over-read)

    k1_seg_offsets<<<(N + 255) / 256, 256, 0, stream>>>(index, seg_start, N, S);
    k2_seg_softmax_pool<<<(S + 3) / 4, 256, 0, stream>>>(x, weights, Wg, bg, pow_,
                                                         seg_start, t, sgate, S);
    k3_out_gemm<<<(S + 63) / 64, 512, 0, stream>>>(t, Wm, bm, sgate, out, S);
}